// Round 1
// 495.446 us; speedup vs baseline: 1.0716x; 1.0716x over previous
//
#include <hip/hip_runtime.h>
#include <hip/hip_bf16.h>
#include <math.h>

// Problem constants (from reference)
#define N_VARS    100000
#define D_DIM     512
#define C_CLUST   4096
#define K_VARS    32
#define E_EDGES   16384
#define S_SHARED  16
#define H_HEADS   4
#define CAP       32      // max contributions tracked per var (Poisson(2.62) -> P(>=32) ~ 1e-26)
#define NEG_SLOPE 0.2f

typedef __bf16 bf16x8_t __attribute__((ext_vector_type(8)));
typedef float  f32x4_t  __attribute__((ext_vector_type(4)));

__device__ __forceinline__ unsigned int f32_to_bf16_bits(float f) {
    unsigned int u = __builtin_bit_cast(unsigned int, f);
    unsigned int lsb = (u >> 16) & 1u;
    u += 0x7fffu + lsb;   // round-to-nearest-even
    return u >> 16;
}
__device__ __forceinline__ unsigned int pack_bf16x2(float a, float b) {
    return (f32_to_bf16_bits(b) << 16) | f32_to_bf16_bits(a);
}
__device__ __forceinline__ float bf16_bits_to_f32(unsigned int h) {
    unsigned int u = h << 16;
    return __builtin_bit_cast(float, u);
}

// Robust decode of the active_heads scalar (int expected; tolerate float encoding).
__device__ __forceinline__ int decode_active_heads(const int* p) {
    int raw = p[0];
    if (raw >= 1 && raw <= H_HEADS) return raw;
    float f = __builtin_bit_cast(float, raw);
    if (f >= 1.0f && f <= (float)H_HEADS) return (int)f;
    return H_HEADS;
}

// ---------------------------------------------------------------------------
// 0) Convert the three 512x512 f32 weight matrices to bf16 (packed u32 pairs).
__global__ void convert_w_kernel(const float* __restrict__ Wq,
                                 const float* __restrict__ Wk,
                                 const float* __restrict__ Wv,
                                 unsigned int* __restrict__ Wb) {
    const float* W = (blockIdx.y == 0) ? Wq : (blockIdx.y == 1) ? Wk : Wv;
    int i = blockIdx.x * blockDim.x + threadIdx.x;         // word index [0, 512*512/2)
    float2 w = ((const float2*)W)[i];
    Wb[(size_t)blockIdx.y * (D_DIM * D_DIM / 2) + i] = pack_bf16x2(w.x, w.y);
}

// ---------------------------------------------------------------------------
// 1) Per-cluster mean pool. 2 clusters per 256-block; 128 threads/cluster,
//    thread handles dims 4t..4t+3 via float4 (16 B/lane).
//    Also zeroes counts[] (grid covers N_VARS), replacing the memset dispatch.
__global__ void pool_kernel(const float* __restrict__ x,
                            const int* __restrict__ cvid,
                            uint2* __restrict__ cfb /* packed bf16, 4/entry */,
                            int* __restrict__ counts) {
    int gtid = blockIdx.x * blockDim.x + threadIdx.x;
    if (gtid < N_VARS) counts[gtid] = 0;

    int c = blockIdx.x * 2 + (threadIdx.x >> 7);
    c = __builtin_amdgcn_readfirstlane(c);   // wave-uniform -> scalar id loads
    int t = threadIdx.x & 127;  // float4 index within row
    const int* cv = cvid + c * K_VARS;
    float4 acc = {0.f, 0.f, 0.f, 0.f};
#pragma unroll 8
    for (int k = 0; k < K_VARS; ++k) {
        int v = cv[k];                       // s_load (scalar addr)
        float4 w = ((const float4*)(x + (size_t)v * D_DIM))[t];
        acc.x += w.x; acc.y += w.y; acc.z += w.z; acc.w += w.w;
    }
    const float inv = 1.0f / (float)K_VARS;
    uint2 o;
    o.x = pack_bf16x2(acc.x * inv, acc.y * inv);
    o.y = pack_bf16x2(acc.z * inv, acc.w * inv);
    cfb[(size_t)c * (D_DIM / 4) + t] = o;
}

// ---------------------------------------------------------------------------
// 2) QKV GEMM via MFMA 16x16x32 bf16. O[m,n] = sum_k cf[m,k] * W[n,k].
//    Block = 4 waves; block tile 64(m) x 64(n). Wave w: rows w*16..+16, all
//    64 cols as 4 independent acc chains (A fragment reused 4x). z = Q/K/V.
__global__ __launch_bounds__(256) void gemm_kernel(
        const unsigned short* __restrict__ cfb,
        const unsigned short* __restrict__ Wb,
        float* __restrict__ Qo, float* __restrict__ Ko, float* __restrict__ Vo) {
    const unsigned short* W = Wb + (size_t)blockIdx.z * D_DIM * D_DIM;
    float* O = (blockIdx.z == 0) ? Qo : (blockIdx.z == 1) ? Ko : Vo;

    int wave = threadIdx.x >> 6;
    int lane = threadIdx.x & 63;
    int m0 = blockIdx.x * 64 + wave * 16;
    int n0 = blockIdx.y * 64;
    int mr = m0 + (lane & 15);
    int kb = (lane >> 4) * 8;

    f32x4_t acc0 = {0.f,0.f,0.f,0.f}, acc1 = {0.f,0.f,0.f,0.f};
    f32x4_t acc2 = {0.f,0.f,0.f,0.f}, acc3 = {0.f,0.f,0.f,0.f};
    const unsigned short* arow = cfb + (size_t)mr * D_DIM + kb;
    const unsigned short* b0r  = W + (size_t)(n0 +  0 + (lane & 15)) * D_DIM + kb;
    const unsigned short* b1r  = W + (size_t)(n0 + 16 + (lane & 15)) * D_DIM + kb;
    const unsigned short* b2r  = W + (size_t)(n0 + 32 + (lane & 15)) * D_DIM + kb;
    const unsigned short* b3r  = W + (size_t)(n0 + 48 + (lane & 15)) * D_DIM + kb;
#pragma unroll 4
    for (int k0 = 0; k0 < D_DIM; k0 += 32) {
        bf16x8_t a  = *(const bf16x8_t*)(arow + k0);
        bf16x8_t b0 = *(const bf16x8_t*)(b0r + k0);
        bf16x8_t b1 = *(const bf16x8_t*)(b1r + k0);
        bf16x8_t b2 = *(const bf16x8_t*)(b2r + k0);
        bf16x8_t b3 = *(const bf16x8_t*)(b3r + k0);
        acc0 = __builtin_amdgcn_mfma_f32_16x16x32_bf16(a, b0, acc0, 0, 0, 0);
        acc1 = __builtin_amdgcn_mfma_f32_16x16x32_bf16(a, b1, acc1, 0, 0, 0);
        acc2 = __builtin_amdgcn_mfma_f32_16x16x32_bf16(a, b2, acc2, 0, 0, 0);
        acc3 = __builtin_amdgcn_mfma_f32_16x16x32_bf16(a, b3, acc3, 0, 0, 0);
    }
    // C/D layout: col = lane&15 (n), row = (lane>>4)*4 + reg (m)  [m89-verified]
    int rb = m0 + (lane >> 4) * 4;
    int cl = lane & 15;
#pragma unroll
    for (int r = 0; r < 4; ++r) {
        float* orow = O + (size_t)(rb + r) * D_DIM + n0 + cl;
        orow[ 0] = acc0[r];
        orow[16] = acc1[r];
        orow[32] = acc2[r];
        orow[48] = acc3[r];
    }
}

// ---------------------------------------------------------------------------
// 3) Fused edge attention + scatter-fill. One wave per edge:
//    attn[e] = hw_mean * sigmoid(leaky(QK/sqrt(D))); then lanes 0..15 push the
//    packed (attn_bf16 << 16 | c2) entry into each shared var's bucket.
//    Removes the separate fill dispatch and the attn[] round-trip.
__global__ __launch_bounds__(256) void score_fill_kernel(
        const float* __restrict__ Q,
        const float* __restrict__ Kc,
        const int* __restrict__ cei,
        const float* __restrict__ hw,
        const int* __restrict__ active_heads,
        const int* __restrict__ shared_vars,
        int* __restrict__ counts,
        unsigned int* __restrict__ bucket) {
    int e = __builtin_amdgcn_readfirstlane(blockIdx.x * 4 + (threadIdx.x >> 6));
    int lane = threadIdx.x & 63;
    int c1 = cei[e];
    int c2 = cei[E_EDGES + e];
    const float4* q = (const float4*)(Q  + (size_t)c1 * D_DIM);
    const float4* k = (const float4*)(Kc + (size_t)c2 * D_DIM);
    float4 qa = q[lane], qb = q[lane + 64];
    float4 ka = k[lane], kb = k[lane + 64];
    float s = qa.x*ka.x + qa.y*ka.y + qa.z*ka.z + qa.w*ka.w
            + qb.x*kb.x + qb.y*kb.y + qb.z*kb.z + qb.w*kb.w;
#pragma unroll
    for (int off = 32; off > 0; off >>= 1)
        s += __shfl_xor(s, off);
    // all lanes now hold the full dot product
    int ah = decode_active_heads(active_heads);
    float m = 0.f;
    for (int h = 0; h < ah; ++h) m += hw[h];
    m /= (float)ah;
    float sc = s * (1.0f / sqrtf((float)D_DIM));
    sc = sc >= 0.f ? sc : NEG_SLOPE * sc;
    float attn = m / (1.f + __expf(-sc));
    unsigned int packed = (f32_to_bf16_bits(attn) << 16) | (unsigned int)c2;
    if (lane < S_SHARED) {
        int v = shared_vars[e * S_SHARED + lane];
        int pos = atomicAdd(&counts[v], 1);
        if (pos < CAP) bucket[(size_t)v * CAP + pos] = packed;
    }
}

// ---------------------------------------------------------------------------
// 4) Gather: 1 var per wave (4 vars / 256-block), 2x float4 per lane.
//    out[v,:] = x[v,:] + sum attn*V[c2,:].
//    Bucket entries consumed 4 at a time (scalar uint4 load) and all V-row
//    loads of a group issued before accumulation -> 4x memory-level
//    parallelism on the previously serial bucket->V dependent chain.
__global__ __launch_bounds__(256) void gather_kernel(
        const float* __restrict__ x,
        const float* __restrict__ V,
        const int* __restrict__ counts,
        const unsigned int* __restrict__ bucket,
        float* __restrict__ out) {
    int v = __builtin_amdgcn_readfirstlane(blockIdx.x * 4 + (threadIdx.x >> 6));
    int lane = threadIdx.x & 63;
    const f32x4_t* xr = (const f32x4_t*)(x + (size_t)v * D_DIM);
    f32x4_t a0 = xr[lane];
    f32x4_t a1 = xr[lane + 64];
    int cnt = counts[v];
    if (cnt > CAP) cnt = CAP;
    const unsigned int* bk = bucket + (size_t)v * CAP;
    for (int k = 0; k < cnt; k += 4) {
        uint4 pw = *(const uint4*)(bk + k);   // scalar addr -> s_load_dwordx4
        int m = cnt - k;                      // wave-uniform
        const f32x4_t* r0 = (const f32x4_t*)(V + (size_t)(pw.x & 0xFFFu) * D_DIM);
        f32x4_t u0a = r0[lane], u0b = r0[lane + 64];
        f32x4_t u1a, u1b, u2a, u2b, u3a, u3b;
        if (m > 1) {
            const f32x4_t* r1 = (const f32x4_t*)(V + (size_t)(pw.y & 0xFFFu) * D_DIM);
            u1a = r1[lane]; u1b = r1[lane + 64];
        }
        if (m > 2) {
            const f32x4_t* r2 = (const f32x4_t*)(V + (size_t)(pw.z & 0xFFFu) * D_DIM);
            u2a = r2[lane]; u2b = r2[lane + 64];
        }
        if (m > 3) {
            const f32x4_t* r3 = (const f32x4_t*)(V + (size_t)(pw.w & 0xFFFu) * D_DIM);
            u3a = r3[lane]; u3b = r3[lane + 64];
        }
        float t0 = bf16_bits_to_f32(pw.x >> 16);
        a0 += t0 * u0a; a1 += t0 * u0b;
        if (m > 1) { float t1 = bf16_bits_to_f32(pw.y >> 16); a0 += t1 * u1a; a1 += t1 * u1b; }
        if (m > 2) { float t2 = bf16_bits_to_f32(pw.z >> 16); a0 += t2 * u2a; a1 += t2 * u2b; }
        if (m > 3) { float t3 = bf16_bits_to_f32(pw.w >> 16); a0 += t3 * u3a; a1 += t3 * u3b; }
    }
    // out is written once and never re-read: non-temporal keeps x/V hot in L3.
    f32x4_t* orow = (f32x4_t*)(out + (size_t)v * D_DIM);
    __builtin_nontemporal_store(a0, orow + lane);
    __builtin_nontemporal_store(a1, orow + lane + 64);
}

// ---------------------------------------------------------------------------
extern "C" void kernel_launch(void* const* d_in, const int* in_sizes, int n_in,
                              void* d_out, int out_size, void* d_ws, size_t ws_size,
                              hipStream_t stream) {
    const float* x_var = (const float*)d_in[0];
    const float* W_Q   = (const float*)d_in[1];
    const float* W_K   = (const float*)d_in[2];
    const float* W_V   = (const float*)d_in[3];
    const float* hw    = (const float*)d_in[4];
    const int* cvid  = (const int*)d_in[5];
    const int* cei   = (const int*)d_in[6];
    const int* shv   = (const int*)d_in[7];
    const int* ahp   = (const int*)d_in[8];

    char* ws = (char*)d_ws;
    const size_t MiB = 1024 * 1024;
    // workspace layout (~43.3 MiB total, same as known-good R2 footprint)
    unsigned int* cfb = (unsigned int*)(ws + 0);          // bf16 [C,D] packed: 4 MiB
    unsigned int* Wb  = (unsigned int*)(ws + 4  * MiB);   // bf16 3x[D,D] packed: 1.5 MiB
    float* Q    = (float*)(ws + 6  * MiB);                // 8 MiB
    float* Kc   = (float*)(ws + 14 * MiB);                // 8 MiB
    float* V    = (float*)(ws + 22 * MiB);                // 8 MiB
    int* counts = (int*)(ws + 30 * MiB + 65536);          // 400 KB
    unsigned int* bucket = (unsigned int*)(ws + 31 * MiB);// 12.8 MB

    convert_w_kernel<<<dim3(D_DIM * D_DIM / 2 / 256, 3), 256, 0, stream>>>(
        W_Q, W_K, W_V, Wb);

    pool_kernel<<<C_CLUST / 2, 256, 0, stream>>>(x_var, cvid, (uint2*)cfb, counts);

    gemm_kernel<<<dim3(C_CLUST / 64, D_DIM / 64, 3), 256, 0, stream>>>(
        (const unsigned short*)cfb, (const unsigned short*)Wb, Q, Kc, V);

    score_fill_kernel<<<E_EDGES / 4, 256, 0, stream>>>(
        Q, Kc, cei, hw, ahp, shv, counts, bucket);

    gather_kernel<<<N_VARS / 4, 256, 0, stream>>>(x_var, V, counts, bucket,
                                                  (float*)d_out);
}

// Round 2
// 475.090 us; speedup vs baseline: 1.1176x; 1.0428x over previous
//
#include <hip/hip_runtime.h>
#include <hip/hip_bf16.h>
#include <math.h>

// Problem constants (from reference)
#define N_VARS    100000
#define D_DIM     512
#define C_CLUST   4096
#define K_VARS    32
#define E_EDGES   16384
#define S_SHARED  16
#define H_HEADS   4
#define CAP       32      // max contributions tracked per var (Poisson(2.62) -> P(>=32) ~ 1e-26)
#define NEG_SLOPE 0.2f

typedef __bf16 bf16x8_t __attribute__((ext_vector_type(8)));
typedef float  f32x4_t  __attribute__((ext_vector_type(4)));

__device__ __forceinline__ unsigned int f32_to_bf16_bits(float f) {
    unsigned int u = __builtin_bit_cast(unsigned int, f);
    unsigned int lsb = (u >> 16) & 1u;
    u += 0x7fffu + lsb;   // round-to-nearest-even
    return u >> 16;
}
__device__ __forceinline__ unsigned int pack_bf16x2(float a, float b) {
    return (f32_to_bf16_bits(b) << 16) | f32_to_bf16_bits(a);
}
__device__ __forceinline__ float bf16_lo_to_f32(unsigned int w) {
    return __builtin_bit_cast(float, w << 16);
}
__device__ __forceinline__ float bf16_hi_to_f32(unsigned int w) {
    return __builtin_bit_cast(float, w & 0xffff0000u);
}

// Robust decode of the active_heads scalar (int expected; tolerate float encoding).
__device__ __forceinline__ int decode_active_heads(const int* p) {
    int raw = p[0];
    if (raw >= 1 && raw <= H_HEADS) return raw;
    float f = __builtin_bit_cast(float, raw);
    if (f >= 1.0f && f <= (float)H_HEADS) return (int)f;
    return H_HEADS;
}

// ---------------------------------------------------------------------------
// 0) Convert the three 512x512 f32 weight matrices to bf16 (packed u32 pairs).
__global__ void convert_w_kernel(const float* __restrict__ Wq,
                                 const float* __restrict__ Wk,
                                 const float* __restrict__ Wv,
                                 unsigned int* __restrict__ Wb) {
    const float* W = (blockIdx.y == 0) ? Wq : (blockIdx.y == 1) ? Wk : Wv;
    int i = blockIdx.x * blockDim.x + threadIdx.x;         // word index [0, 512*512/2)
    float2 w = ((const float2*)W)[i];
    Wb[(size_t)blockIdx.y * (D_DIM * D_DIM / 2) + i] = pack_bf16x2(w.x, w.y);
}

// ---------------------------------------------------------------------------
// 1) Per-cluster mean pool. 2 clusters per 256-block; 128 threads/cluster,
//    thread handles dims 4t..4t+3 via float4 (16 B/lane).
//    Also zeroes counts[] (grid covers N_VARS), replacing the memset dispatch.
__global__ void pool_kernel(const float* __restrict__ x,
                            const int* __restrict__ cvid,
                            uint2* __restrict__ cfb /* packed bf16, 4/entry */,
                            int* __restrict__ counts) {
    int gtid = blockIdx.x * blockDim.x + threadIdx.x;
    if (gtid < N_VARS) counts[gtid] = 0;

    int c = blockIdx.x * 2 + (threadIdx.x >> 7);
    c = __builtin_amdgcn_readfirstlane(c);   // wave-uniform -> scalar id loads
    int t = threadIdx.x & 127;  // float4 index within row
    const int* cv = cvid + c * K_VARS;
    float4 acc = {0.f, 0.f, 0.f, 0.f};
#pragma unroll 8
    for (int k = 0; k < K_VARS; ++k) {
        int v = cv[k];                       // s_load (scalar addr)
        float4 w = ((const float4*)(x + (size_t)v * D_DIM))[t];
        acc.x += w.x; acc.y += w.y; acc.z += w.z; acc.w += w.w;
    }
    const float inv = 1.0f / (float)K_VARS;
    uint2 o;
    o.x = pack_bf16x2(acc.x * inv, acc.y * inv);
    o.y = pack_bf16x2(acc.z * inv, acc.w * inv);
    cfb[(size_t)c * (D_DIM / 4) + t] = o;
}

// ---------------------------------------------------------------------------
// 2) QKV GEMM via MFMA 16x16x32 bf16. O[m,n] = sum_k cf[m,k] * W[n,k].
//    Block = 4 waves; block tile 64(m) x 64(n). Wave w: rows w*16..+16, all
//    64 cols as 4 independent acc chains (A fragment reused 4x). z = Q/K/V.
//    Q,K written f32 (score consumes once); V written packed bf16 so gather's
//    4 MB V image is per-XCD-L2 resident and one dwordx4 covers 8 dims/lane.
__global__ __launch_bounds__(256) void gemm_kernel(
        const unsigned short* __restrict__ cfb,
        const unsigned short* __restrict__ Wb,
        float* __restrict__ Qo, float* __restrict__ Ko,
        unsigned short* __restrict__ Vb) {
    const unsigned short* W = Wb + (size_t)blockIdx.z * D_DIM * D_DIM;

    int wave = threadIdx.x >> 6;
    int lane = threadIdx.x & 63;
    int m0 = blockIdx.x * 64 + wave * 16;
    int n0 = blockIdx.y * 64;
    int mr = m0 + (lane & 15);
    int kb = (lane >> 4) * 8;

    f32x4_t acc0 = {0.f,0.f,0.f,0.f}, acc1 = {0.f,0.f,0.f,0.f};
    f32x4_t acc2 = {0.f,0.f,0.f,0.f}, acc3 = {0.f,0.f,0.f,0.f};
    const unsigned short* arow = cfb + (size_t)mr * D_DIM + kb;
    const unsigned short* b0r  = W + (size_t)(n0 +  0 + (lane & 15)) * D_DIM + kb;
    const unsigned short* b1r  = W + (size_t)(n0 + 16 + (lane & 15)) * D_DIM + kb;
    const unsigned short* b2r  = W + (size_t)(n0 + 32 + (lane & 15)) * D_DIM + kb;
    const unsigned short* b3r  = W + (size_t)(n0 + 48 + (lane & 15)) * D_DIM + kb;
#pragma unroll 4
    for (int k0 = 0; k0 < D_DIM; k0 += 32) {
        bf16x8_t a  = *(const bf16x8_t*)(arow + k0);
        bf16x8_t b0 = *(const bf16x8_t*)(b0r + k0);
        bf16x8_t b1 = *(const bf16x8_t*)(b1r + k0);
        bf16x8_t b2 = *(const bf16x8_t*)(b2r + k0);
        bf16x8_t b3 = *(const bf16x8_t*)(b3r + k0);
        acc0 = __builtin_amdgcn_mfma_f32_16x16x32_bf16(a, b0, acc0, 0, 0, 0);
        acc1 = __builtin_amdgcn_mfma_f32_16x16x32_bf16(a, b1, acc1, 0, 0, 0);
        acc2 = __builtin_amdgcn_mfma_f32_16x16x32_bf16(a, b2, acc2, 0, 0, 0);
        acc3 = __builtin_amdgcn_mfma_f32_16x16x32_bf16(a, b3, acc3, 0, 0, 0);
    }
    // C/D layout: col = lane&15 (n), row = (lane>>4)*4 + reg (m)  [m89-verified]
    int rb = m0 + (lane >> 4) * 4;
    int cl = lane & 15;
    if (blockIdx.z < 2) {
        float* O = (blockIdx.z == 0) ? Qo : Ko;
#pragma unroll
        for (int r = 0; r < 4; ++r) {
            float* orow = O + (size_t)(rb + r) * D_DIM + n0 + cl;
            orow[ 0] = acc0[r];
            orow[16] = acc1[r];
            orow[32] = acc2[r];
            orow[48] = acc3[r];
        }
    } else {
#pragma unroll
        for (int r = 0; r < 4; ++r) {
            unsigned short* orow = Vb + (size_t)(rb + r) * D_DIM + n0 + cl;
            orow[ 0] = (unsigned short)f32_to_bf16_bits(acc0[r]);
            orow[16] = (unsigned short)f32_to_bf16_bits(acc1[r]);
            orow[32] = (unsigned short)f32_to_bf16_bits(acc2[r]);
            orow[48] = (unsigned short)f32_to_bf16_bits(acc3[r]);
        }
    }
}

// ---------------------------------------------------------------------------
// 3) Fused edge attention + scatter-fill. One wave per edge:
//    attn[e] = hw_mean * sigmoid(leaky(QK/sqrt(D))); then lanes 0..15 push the
//    packed (attn_bf16 << 16 | c2) entry into each shared var's bucket.
__global__ __launch_bounds__(256) void score_fill_kernel(
        const float* __restrict__ Q,
        const float* __restrict__ Kc,
        const int* __restrict__ cei,
        const float* __restrict__ hw,
        const int* __restrict__ active_heads,
        const int* __restrict__ shared_vars,
        int* __restrict__ counts,
        unsigned int* __restrict__ bucket) {
    int e = __builtin_amdgcn_readfirstlane(blockIdx.x * 4 + (threadIdx.x >> 6));
    int lane = threadIdx.x & 63;
    int c1 = cei[e];
    int c2 = cei[E_EDGES + e];
    const float4* q = (const float4*)(Q  + (size_t)c1 * D_DIM);
    const float4* k = (const float4*)(Kc + (size_t)c2 * D_DIM);
    float4 qa = q[lane], qb = q[lane + 64];
    float4 ka = k[lane], kb = k[lane + 64];
    float s = qa.x*ka.x + qa.y*ka.y + qa.z*ka.z + qa.w*ka.w
            + qb.x*kb.x + qb.y*kb.y + qb.z*kb.z + qb.w*kb.w;
#pragma unroll
    for (int off = 32; off > 0; off >>= 1)
        s += __shfl_xor(s, off);
    // all lanes now hold the full dot product
    int ah = decode_active_heads(active_heads);
    float m = 0.f;
    for (int h = 0; h < ah; ++h) m += hw[h];
    m /= (float)ah;
    float sc = s * (1.0f / sqrtf((float)D_DIM));
    sc = sc >= 0.f ? sc : NEG_SLOPE * sc;
    float attn = m / (1.f + __expf(-sc));
    unsigned int packed = (f32_to_bf16_bits(attn) << 16) | (unsigned int)c2;
    if (lane < S_SHARED) {
        int v = shared_vars[e * S_SHARED + lane];
        int pos = atomicAdd(&counts[v], 1);
        if (pos < CAP) bucket[(size_t)v * CAP + pos] = packed;
    }
}

// ---------------------------------------------------------------------------
// 4) Gather: 1 var per wave (4 vars / 256-block). Lane owns dims
//    [8*lane, 8*lane+8): two consecutive float4 of x, ONE dwordx4 of bf16 V
//    per contribution. counts + bucket[0..3] + x issued concurrently (chain
//    depth 2: bucket -> V); next bucket quad prefetched before accumulation.
__global__ __launch_bounds__(256) void gather_kernel(
        const float* __restrict__ x,
        const unsigned short* __restrict__ V,
        const int* __restrict__ counts,
        const unsigned int* __restrict__ bucket,
        float* __restrict__ out) {
    int v = __builtin_amdgcn_readfirstlane(blockIdx.x * 4 + (threadIdx.x >> 6));
    int lane = threadIdx.x & 63;
    const f32x4_t* xr = (const f32x4_t*)(x + (size_t)v * D_DIM);
    f32x4_t a0 = xr[2 * lane];          // dims 8l..8l+3
    f32x4_t a1 = xr[2 * lane + 1];      // dims 8l+4..8l+7
    int cnt = counts[v];
    if (cnt > CAP) cnt = CAP;
    const unsigned int* bk = bucket + (size_t)v * CAP;
    uint4 pw = *(const uint4*)bk;       // unconditional: issued alongside counts/x

    int k = 0;
    while (k < cnt) {
        int m = cnt - k;                // wave-uniform
        // Issue all V-row loads of this group before any accumulation (MLP).
        uint4 w0, w1, w2, w3;
        w0 = ((const uint4*)(V + (size_t)(pw.x & 0xFFFu) * D_DIM))[lane];
        if (m > 1) w1 = ((const uint4*)(V + (size_t)(pw.y & 0xFFFu) * D_DIM))[lane];
        if (m > 2) w2 = ((const uint4*)(V + (size_t)(pw.z & 0xFFFu) * D_DIM))[lane];
        if (m > 3) w3 = ((const uint4*)(V + (size_t)(pw.w & 0xFFFu) * D_DIM))[lane];
        // Prefetch next bucket quad (scalar) before the VALU tail.
        uint4 pwn;
        int kn = k + 4;
        if (kn < cnt) pwn = *(const uint4*)(bk + kn);

        float t0 = bf16_hi_to_f32(pw.x >> 16 << 16);  // attn bf16 in hi16
        {
            float at = __builtin_bit_cast(float, pw.x & 0xffff0000u);
            a0[0] += at * bf16_lo_to_f32(w0.x); a0[1] += at * bf16_hi_to_f32(w0.x);
            a0[2] += at * bf16_lo_to_f32(w0.y); a0[3] += at * bf16_hi_to_f32(w0.y);
            a1[0] += at * bf16_lo_to_f32(w0.z); a1[1] += at * bf16_hi_to_f32(w0.z);
            a1[2] += at * bf16_lo_to_f32(w0.w); a1[3] += at * bf16_hi_to_f32(w0.w);
        }
        if (m > 1) {
            float at = __builtin_bit_cast(float, pw.y & 0xffff0000u);
            a0[0] += at * bf16_lo_to_f32(w1.x); a0[1] += at * bf16_hi_to_f32(w1.x);
            a0[2] += at * bf16_lo_to_f32(w1.y); a0[3] += at * bf16_hi_to_f32(w1.y);
            a1[0] += at * bf16_lo_to_f32(w1.z); a1[1] += at * bf16_hi_to_f32(w1.z);
            a1[2] += at * bf16_lo_to_f32(w1.w); a1[3] += at * bf16_hi_to_f32(w1.w);
        }
        if (m > 2) {
            float at = __builtin_bit_cast(float, pw.z & 0xffff0000u);
            a0[0] += at * bf16_lo_to_f32(w2.x); a0[1] += at * bf16_hi_to_f32(w2.x);
            a0[2] += at * bf16_lo_to_f32(w2.y); a0[3] += at * bf16_hi_to_f32(w2.y);
            a1[0] += at * bf16_lo_to_f32(w2.z); a1[1] += at * bf16_hi_to_f32(w2.z);
            a1[2] += at * bf16_lo_to_f32(w2.w); a1[3] += at * bf16_hi_to_f32(w2.w);
        }
        if (m > 3) {
            float at = __builtin_bit_cast(float, pw.w & 0xffff0000u);
            a0[0] += at * bf16_lo_to_f32(w3.x); a0[1] += at * bf16_hi_to_f32(w3.x);
            a0[2] += at * bf16_lo_to_f32(w3.y); a0[3] += at * bf16_hi_to_f32(w3.y);
            a1[0] += at * bf16_lo_to_f32(w3.z); a1[1] += at * bf16_hi_to_f32(w3.z);
            a1[2] += at * bf16_lo_to_f32(w3.w); a1[3] += at * bf16_hi_to_f32(w3.w);
        }
        (void)t0;
        pw = pwn;
        k = kn;
    }
    // out is written once and never re-read: non-temporal keeps x/V hot in cache.
    f32x4_t* orow = (f32x4_t*)(out + (size_t)v * D_DIM);
    __builtin_nontemporal_store(a0, orow + 2 * lane);
    __builtin_nontemporal_store(a1, orow + 2 * lane + 1);
}

// ---------------------------------------------------------------------------
extern "C" void kernel_launch(void* const* d_in, const int* in_sizes, int n_in,
                              void* d_out, int out_size, void* d_ws, size_t ws_size,
                              hipStream_t stream) {
    const float* x_var = (const float*)d_in[0];
    const float* W_Q   = (const float*)d_in[1];
    const float* W_K   = (const float*)d_in[2];
    const float* W_V   = (const float*)d_in[3];
    const float* hw    = (const float*)d_in[4];
    const int* cvid  = (const int*)d_in[5];
    const int* cei   = (const int*)d_in[6];
    const int* shv   = (const int*)d_in[7];
    const int* ahp   = (const int*)d_in[8];

    char* ws = (char*)d_ws;
    const size_t MiB = 1024 * 1024;
    // workspace layout (~44 MiB total)
    unsigned int* cfb = (unsigned int*)(ws + 0);          // bf16 [C,D] packed: 4 MiB
    unsigned int* Wb  = (unsigned int*)(ws + 4  * MiB);   // bf16 3x[D,D] packed: 1.5 MiB
    float* Q    = (float*)(ws + 6  * MiB);                // 8 MiB
    float* Kc   = (float*)(ws + 14 * MiB);                // 8 MiB
    unsigned short* Vb = (unsigned short*)(ws + 22 * MiB);// bf16 [C,D]: 4 MiB
    int* counts = (int*)(ws + 30 * MiB + 65536);          // 400 KB
    unsigned int* bucket = (unsigned int*)(ws + 31 * MiB);// 12.8 MB

    convert_w_kernel<<<dim3(D_DIM * D_DIM / 2 / 256, 3), 256, 0, stream>>>(
        W_Q, W_K, W_V, Wb);

    pool_kernel<<<C_CLUST / 2, 256, 0, stream>>>(x_var, cvid, (uint2*)cfb, counts);

    gemm_kernel<<<dim3(C_CLUST / 64, D_DIM / 64, 3), 256, 0, stream>>>(
        (const unsigned short*)cfb, (const unsigned short*)Wb, Q, Kc, Vb);

    score_fill_kernel<<<E_EDGES / 4, 256, 0, stream>>>(
        Q, Kc, cei, hw, ahp, shv, counts, bucket);

    gather_kernel<<<N_VARS / 4, 256, 0, stream>>>(x_var, Vb, counts, bucket,
                                                  (float*)d_out);
}